// Round 1
// baseline (404.381 us; speedup 1.0000x reference)
//
#include <hip/hip_runtime.h>
#include <hip/hip_bf16.h>
#include <stdint.h>

#define B_DIM   8192
#define IN_DIM  4096
#define OUT_DIM 4096
#define BSZ     64
#define NBR_    64
#define BPR_    16
#define KTOT    1024   // BPR_*BSZ
#define MT      256    // batch tile
#define BKK     32     // K tile (one mfma K)

typedef __attribute__((ext_vector_type(4))) float  floatx4;
typedef __attribute__((ext_vector_type(8))) short  shortx8;  // 8 bf16 (4 VGPRs)
typedef __attribute__((ext_vector_type(4))) float  fragc;    // 4 fp32 acc

__device__ __forceinline__ unsigned short f2bf(float f) {
  __bf16 b = (__bf16)f;  // RTNE via hardware cvt
  return __builtin_bit_cast(unsigned short, b);
}

__device__ __forceinline__ void gload_lds16(const void* g, void* l) {
  // 16B per lane, dest = wave-uniform LDS base + lane*16
  __builtin_amdgcn_global_load_lds(
      (const __attribute__((address_space(1))) unsigned int*)g,
      (__attribute__((address_space(3))) unsigned int*)l, 16, 0, 0);
}

// ---------------- fp32 -> bf16 conversion (8 floats / thread / iter) -------
__global__ __launch_bounds__(256) void cvt_kernel(const float* __restrict__ src,
                                                  unsigned short* __restrict__ dst,
                                                  int n8) {
  const int stride = gridDim.x * blockDim.x;
  for (int i = blockIdx.x * blockDim.x + threadIdx.x; i < n8; i += stride) {
    floatx4 a = ((const floatx4*)src)[2 * i];
    floatx4 b = ((const floatx4*)src)[2 * i + 1];
    uint4 o;
    o.x = (unsigned int)f2bf(a.x) | ((unsigned int)f2bf(a.y) << 16);
    o.y = (unsigned int)f2bf(a.z) | ((unsigned int)f2bf(a.w) << 16);
    o.z = (unsigned int)f2bf(b.x) | ((unsigned int)f2bf(b.y) << 16);
    o.w = (unsigned int)f2bf(b.z) | ((unsigned int)f2bf(b.w) << 16);
    ((uint4*)dst)[i] = o;
  }
}

// ---------------- block-sparse GEMM ----------------------------------------
// tile: MT=256 batch rows x 64 out cols (one block-row r). 4 waves, each wave
// computes 64x64 via 4x4 grid of 16x16x32 bf16 MFMAs. K = 16 gathered blocks
// of 64 -> 32 K-steps of BK=32.
template <bool PRECONV>
__global__ __launch_bounds__(256, 3)
void bsr_gemm(const void* __restrict__ xin, const void* __restrict__ vin,
              const float* __restrict__ bias, const int* __restrict__ colidx,
              float* __restrict__ out) {
  const int r  = blockIdx.x;        // block-row 0..63
  const int m0 = blockIdx.y * MT;   // batch tile base
  const int tid  = threadIdx.x;
  const int wave = tid >> 6;
  const int lane = tid & 63;
  const int l16  = lane & 15;
  const int quad = lane >> 4;

  __shared__ __align__(16) unsigned short As[MT * BKK];   // [row][k], 64B rows
  __shared__ __align__(16) unsigned short Bs[BSZ * BKK];  // [n][k],   64B rows
  __shared__ int scols[BPR_];

  if (tid < BPR_) scols[tid] = colidx[r * BPR_ + tid];

  fragc acc[4][4] = {};

  __syncthreads();  // scols visible

  for (int ks = 0; ks < KTOT / BKK; ++ks) {
    const int jb  = ks >> 1;
    const int kb0 = (ks & 1) * BKK;
    const int colbase = scols[jb] * BSZ + kb0;  // gathered column base in x

    __syncthreads();  // previous iteration's LDS reads complete

    if constexpr (PRECONV) {
      const unsigned short* xb = (const unsigned short*)xin;
      const unsigned short* vb = (const unsigned short*)vin;
      const int sub = lane >> 2;        // row within 16-row chunk
      const int kc  = (lane & 3) * 8;   // 8-elem k chunk
      // A: 4 issues/wave, each = 16 rows x 32 k (1KB)
      #pragma unroll
      for (int i = 0; i < 4; ++i) {
        const int row = wave * 64 + i * 16 + sub;
        gload_lds16(xb + (size_t)(m0 + row) * IN_DIM + colbase + kc,
                    &As[(wave * 64 + i * 16) * BKK]);
      }
      // B: 1 issue/wave: values block jb, rows (n) wave*16..+16
      gload_lds16(vb + ((size_t)(r * BPR_ + jb) * BSZ + wave * 16 + sub) * BSZ + kb0 + kc,
                  &Bs[(wave * 16) * BKK]);
    } else {
      const float* x = (const float*)xin;
      const float* v = (const float*)vin;
      const int arow = tid >> 3;        // 0..31
      const int acol = (tid & 7) * 4;   // 0..28 step 4
      #pragma unroll
      for (int i = 0; i < 8; ++i) {
        const int row = i * 32 + arow;
        floatx4 f = *(const floatx4*)&x[(size_t)(m0 + row) * IN_DIM + colbase + acol];
        uint2 p;
        p.x = (unsigned int)f2bf(f.x) | ((unsigned int)f2bf(f.y) << 16);
        p.y = (unsigned int)f2bf(f.z) | ((unsigned int)f2bf(f.w) << 16);
        *(uint2*)&As[row * BKK + acol] = p;
      }
      #pragma unroll
      for (int i = 0; i < 2; ++i) {
        const int row = i * 32 + arow;
        floatx4 f = *(const floatx4*)&v[((size_t)(r * BPR_ + jb) * BSZ + row) * BSZ + kb0 + acol];
        uint2 p;
        p.x = (unsigned int)f2bf(f.x) | ((unsigned int)f2bf(f.y) << 16);
        p.y = (unsigned int)f2bf(f.z) | ((unsigned int)f2bf(f.w) << 16);
        *(uint2*)&Bs[row * BKK + acol] = p;
      }
    }

    __syncthreads();  // staging (incl. async global_load_lds) complete

    shortx8 af[4], bfv[4];
    #pragma unroll
    for (int mi = 0; mi < 4; ++mi)
      af[mi] = *(const shortx8*)&As[(wave * 64 + mi * 16 + l16) * BKK + quad * 8];
    #pragma unroll
    for (int ni = 0; ni < 4; ++ni)
      bfv[ni] = *(const shortx8*)&Bs[(ni * 16 + l16) * BKK + quad * 8];
    #pragma unroll
    for (int mi = 0; mi < 4; ++mi) {
      #pragma unroll
      for (int ni = 0; ni < 4; ++ni)
        acc[mi][ni] = __builtin_amdgcn_mfma_f32_16x16x32_bf16(af[mi], bfv[ni],
                                                              acc[mi][ni], 0, 0, 0);
    }
  }

  // epilogue: C/D layout col=lane&15, row=quad*4+reg (verified m89/m91)
  #pragma unroll
  for (int ni = 0; ni < 4; ++ni) {
    const int col = r * BSZ + ni * 16 + l16;
    const float bv = bias[col];
    #pragma unroll
    for (int mi = 0; mi < 4; ++mi) {
      #pragma unroll
      for (int reg = 0; reg < 4; ++reg) {
        const int row = m0 + wave * 64 + mi * 16 + quad * 4 + reg;
        out[(size_t)row * OUT_DIM + col] = acc[mi][ni][reg] + bv;
      }
    }
  }
}

extern "C" void kernel_launch(void* const* d_in, const int* in_sizes, int n_in,
                              void* d_out, int out_size, void* d_ws, size_t ws_size,
                              hipStream_t stream) {
  const float* x    = (const float*)d_in[0];
  const float* vals = (const float*)d_in[1];
  const float* bias = (const float*)d_in[2];
  const int*   cols = (const int*)d_in[3];
  float* out = (float*)d_out;

  const size_t x_elems = (size_t)B_DIM * IN_DIM;              // 33.5M
  const size_t v_elems = (size_t)NBR_ * BPR_ * BSZ * BSZ;     // 4.2M
  const size_t xb_bytes = x_elems * sizeof(unsigned short);   // 64 MB
  const size_t vb_bytes = v_elems * sizeof(unsigned short);   // 8 MB

  dim3 grid(NBR_, B_DIM / MT);  // r fastest -> blocks sharing a batch tile co-dispatch

  if (ws_size >= xb_bytes + vb_bytes) {
    unsigned short* xb = (unsigned short*)d_ws;
    unsigned short* vb = (unsigned short*)((char*)d_ws + xb_bytes);
    cvt_kernel<<<dim3(8192), dim3(256), 0, stream>>>(x, xb, (int)(x_elems / 8));
    cvt_kernel<<<dim3(2048), dim3(256), 0, stream>>>(vals, vb, (int)(v_elems / 8));
    bsr_gemm<true><<<grid, dim3(256), 0, stream>>>(xb, vb, bias, cols, out);
  } else {
    bsr_gemm<false><<<grid, dim3(256), 0, stream>>>(x, vals, bias, cols, out);
  }
}